// Round 2
// baseline (2995.658 us; speedup 1.0000x reference)
//
#include <hip/hip_runtime.h>
#include <hip/hip_bf16.h>

#define BATCH 16
#define CH 32
#define HH 256
#define WW 256
#define NPIX (BATCH*HH*WW)   // 1,048,576
#define NCODES 256
#define NSTEPS 5
#define LST 33               // tile pixel stride (floats): 33 breaks 32-bank aliasing

using u16 = unsigned short;
using u32 = unsigned int;
using u8  = unsigned char;

__device__ __forceinline__ float bf2f(u32 u) {
    union { u32 i; float f; } v; v.i = u << 16; return v.f;
}
__device__ __forceinline__ u16 f2bf(float f) {
    union { float f; u32 i; } v; v.f = f;
    u32 x = v.i;
    x += 0x7fffu + ((x >> 16) & 1u);
    return (u16)(x >> 16);
}
// dtype-agnostic input element load: f32 flag selects float32 vs bf16 layout
__device__ __forceinline__ float ldin(const void* p, int i, int f32) {
    return f32 ? ((const float*)p)[i] : bf2f(((const u16*)p)[i]);
}
// sniff input dtype from raw words of x (per-thread, deterministic):
// bf16-pair words have a sane bf16 in their low half; fp32 words have random
// mantissa bits there (uniform exponent -> almost never sane magnitude).
__device__ __forceinline__ int sniff_f32(const void* xraw) {
    const u32* xw = (const u32*)xraw;
    int cnt = 0;
    for (int j = 0; j < 64; j++) {
        u32 w = xw[j];
        float flo = bf2f(w & 0xffffu);
        float a = fabsf(flo);
        if (flo == 0.0f || (a >= 6e-8f && a <= 64.0f)) cnt++;
    }
    return (cnt < 32) ? 1 : 0;
}

// ws float layout:
// wf1[(tap*32+ci)*32+co] 9216 | wf2[co*32+ci] 1024 | wft[co*32+ci] 1024
// cbf[k*32+c] 8192 | cn2[k] 256 | wf0[tap*32+co] 288
// bias_all: [0:32) up1_b | [32:64) tau_b | [64:96) up2_b | [96:128) stem_b
//           [128:160) dec_w | [160] dec_b
__global__ void prep_kernel(const void* x,
                            const void* stem_w, const void* stem_b,
                            const void* up1_w, const void* up1_b,
                            const void* up2_w, const void* up2_b,
                            const void* tau_w, const void* tau_b,
                            const void* cb, const void* dec_w, const void* dec_b,
                            float* wf1, float* wf2, float* wft,
                            float* cbf, float* cn2, float* wf0, float* bias_all,
                            int* flag)
{
    int f32 = sniff_f32(x);
    int i = blockIdx.x * 256 + threadIdx.x;
    if (i == 0) *flag = f32;
    if (i < 9216) {                      // from up1_w (co,ci,ky,kx)
        int tap = i / 1024; int r = i - tap*1024; int ci = r >> 5, co = r & 31;
        wf1[i] = ldin(up1_w, (co*32 + ci)*9 + tap, f32);
        return;
    }
    i -= 9216;
    if (i < 1024) { wf2[i] = ldin(up2_w, i, f32); return; }
    i -= 1024;
    if (i < 1024) { wft[i] = ldin(tau_w, i, f32); return; }
    i -= 1024;
    if (i < 8192) { cbf[i] = ldin(cb, i, f32); return; }
    i -= 8192;
    if (i < 256) {
        float s = 0.f;
        for (int c = 0; c < 32; c++) { float v = ldin(cb, i*32 + c, f32); s += v*v; }
        cn2[i] = 0.5f * s;
        return;
    }
    i -= 256;
    if (i < 288) {                       // from stem_w (co,1,ky,kx)
        int tap = i >> 5, co = i & 31;
        wf0[i] = ldin(stem_w, co*9 + tap, f32);
        return;
    }
    i -= 288;
    if (i < 32) { bias_all[i]      = ldin(up1_b, i, f32); return; }
    i -= 32;
    if (i < 32) { bias_all[32+i]   = ldin(tau_b, i, f32); return; }
    i -= 32;
    if (i < 32) { bias_all[64+i]   = ldin(up2_b, i, f32); return; }
    i -= 32;
    if (i < 32) { bias_all[96+i]   = ldin(stem_b, i, f32); return; }
    i -= 32;
    if (i < 32) { bias_all[128+i]  = ldin(dec_w, i, f32); return; }
    i -= 32;
    if (i == 0) { bias_all[160] = ldin(dec_b, 0, f32); }
}

// One full NCA step, fused: conv3x3+relu -> up2 / tau -> sigmoid blend -> VQ.
// mode 0: state tile computed from x via the stem conv (first step).
// mode 1: state tile gathered as codebook[idx_in] (steps 2..n).
// Output: idx_out[pixel] = argmin code (u8).
__global__ __launch_bounds__(256) void step_kernel(
        int mode, const void* __restrict__ xraw, const int* __restrict__ flagp,
        const u8* __restrict__ idx_in, u8* __restrict__ idx_out,
        const float* __restrict__ wf0, const float* __restrict__ wf1,
        const float* __restrict__ wf2, const float* __restrict__ wft,
        const float* __restrict__ cbf, const float* __restrict__ cn2,
        const float* __restrict__ bias_all)
{
    __shared__ float tile[324 * LST];   // 18x18 pixels x 32ch (stride 33)
    __shared__ float xs[400];           // 20x20 x-halo (mode 0)
    int tid = threadIdx.x;
    int tx = tid & 15, ty = tid >> 4;
    int x0 = blockIdx.x * 16, y0 = blockIdx.y * 16, b = blockIdx.z;

    if (mode == 0) {
        int f32 = *flagp;
        for (int pp = tid; pp < 400; pp += 256) {
            int r = pp / 20, c = pp - r*20;
            int gy = y0 - 2 + r, gx = x0 - 2 + c;
            float v = 0.f;
            if ((unsigned)gy < HH && (unsigned)gx < WW)
                v = ldin(xraw, (b << 16) | (gy << 8) | gx, f32);
            xs[pp] = v;
        }
        __syncthreads();
        for (int pp = tid; pp < 324; pp += 256) {
            int r = pp / 18, c = pp - r*18;
            int gy = y0 - 1 + r, gx = x0 - 1 + c;
            float* d = &tile[pp * LST];
            if ((unsigned)gy < HH && (unsigned)gx < WW) {
                float acc[32];
#pragma unroll
                for (int co = 0; co < 32; co++) acc[co] = bias_all[96 + co];
#pragma unroll
                for (int tap = 0; tap < 9; tap++) {
                    float v = xs[(r + tap/3)*20 + (c + tap%3)];
                    const float* w = &wf0[tap*32];
#pragma unroll
                    for (int co = 0; co < 32; co++) acc[co] = fmaf(v, w[co], acc[co]);
                }
#pragma unroll
                for (int co = 0; co < 32; co++) d[co] = fmaxf(acc[co], 0.f);
            } else {
#pragma unroll
                for (int co = 0; co < 32; co++) d[co] = 0.f;
            }
        }
    } else {
        for (int pp = tid; pp < 324; pp += 256) {
            int r = pp / 18, c = pp - r*18;
            int gy = y0 - 1 + r, gx = x0 - 1 + c;
            float* d = &tile[pp * LST];
            if ((unsigned)gy < HH && (unsigned)gx < WW) {
                int k = idx_in[(b << 16) | (gy << 8) | gx];
                const float* cr = &cbf[k*32];
#pragma unroll
                for (int c2 = 0; c2 < 32; c2++) d[c2] = cr[c2];
            } else {
#pragma unroll
                for (int c2 = 0; c2 < 32; c2++) d[c2] = 0.f;
            }
        }
    }
    __syncthreads();

    // h = relu(conv3x3(state) + up1_b)
    float h[32];
#pragma unroll
    for (int co = 0; co < 32; co++) h[co] = bias_all[co];
    int base = (ty*18 + tx) * LST;
#pragma unroll
    for (int tap = 0; tap < 9; tap++) {
        const float* t0 = &tile[base + ((tap/3)*18 + (tap%3)) * LST];
        const float* wt = &wf1[tap * 1024];
        for (int ci = 0; ci < 32; ci++) {
            float v = t0[ci];
            const float* wrow = &wt[ci*32];
#pragma unroll
            for (int co = 0; co < 32; co++) h[co] = fmaf(v, wrow[co], h[co]);
        }
    }
#pragma unroll
    for (int co = 0; co < 32; co++) h[co] = fmaxf(h[co], 0.f);

    // s = current state at this pixel
    float s[32];
    const float* ct = &tile[((ty+1)*18 + (tx+1)) * LST];
#pragma unroll
    for (int c = 0; c < 32; c++) s[c] = ct[c];

    // delta / beta / blend
    float z[32];
#pragma unroll
    for (int co = 0; co < 32; co++) {
        const float* w2 = &wf2[co*32];
        const float* wt = &wft[co*32];
        float da = bias_all[64+co], db = 0.f;
        float ta = bias_all[32+co], tb = 0.f;
#pragma unroll
        for (int ci = 0; ci < 32; ci += 2) {
            da = fmaf(h[ci],   w2[ci],   da);
            db = fmaf(h[ci+1], w2[ci+1], db);
            ta = fmaf(s[ci],   wt[ci],   ta);
            tb = fmaf(s[ci+1], wt[ci+1], tb);
        }
        float dlt  = da + db;
        float tt   = ta + tb;
        float beta = 1.0f / (1.0f + __expf(-tt));
        z[co] = beta * s[co] + (1.0f - beta) * dlt;
    }

    // VQ argmin_k (0.5||c_k||^2 - z.c_k)  (monotone-equal to ref distance)
    float best_d = 1e30f; int best = 0;
    for (int k = 0; k < NCODES; k++) {
        const float* ck = &cbf[k*32];
        float d0 = 0.f, d1 = 0.f, d2 = 0.f, d3 = 0.f;
#pragma unroll
        for (int c = 0; c < 32; c += 4) {
            d0 = fmaf(z[c],   ck[c],   d0);
            d1 = fmaf(z[c+1], ck[c+1], d1);
            d2 = fmaf(z[c+2], ck[c+2], d2);
            d3 = fmaf(z[c+3], ck[c+3], d3);
        }
        float dist = cn2[k] - ((d0+d1)+(d2+d3));
        if (dist < best_d) { best_d = dist; best = k; }
    }
    idx_out[(b << 16) | ((y0 + ty) << 8) | (x0 + tx)] = (u8)best;
}

// dec: out = sigmoid(dec_w . codebook[idx] + dec_b), stored per dtype flag
__global__ __launch_bounds__(256) void dec_kernel(const u8* __restrict__ idx,
        const float* __restrict__ cbf, const float* __restrict__ bias_all,
        const int* __restrict__ flagp, void* __restrict__ out)
{
    int p = blockIdx.x * 256 + threadIdx.x;
    int k = idx[p];
    const float* cr = &cbf[k*32];
    float a0 = 0.f, a1 = 0.f, a2 = 0.f, a3 = 0.f;
#pragma unroll
    for (int c = 0; c < 32; c += 4) {
        a0 = fmaf(cr[c],   bias_all[128+c],   a0);
        a1 = fmaf(cr[c+1], bias_all[128+c+1], a1);
        a2 = fmaf(cr[c+2], bias_all[128+c+2], a2);
        a3 = fmaf(cr[c+3], bias_all[128+c+3], a3);
    }
    float sum = (a0+a1) + (a2+a3) + bias_all[160];
    float r = 1.0f / (1.0f + __expf(-sum));
    if (*flagp) ((float*)out)[p] = r;
    else        ((u16*)out)[p]   = f2bf(r);
}

extern "C" void kernel_launch(void* const* d_in, const int* in_sizes, int n_in,
                              void* d_out, int out_size, void* d_ws, size_t ws_size,
                              hipStream_t stream)
{
    const void* x      = d_in[0];
    const void* stem_w = d_in[1];
    const void* stem_b = d_in[2];
    const void* up1_w  = d_in[3];
    const void* up1_b  = d_in[4];
    const void* up2_w  = d_in[5];
    const void* up2_b  = d_in[6];
    const void* tau_w  = d_in[7];
    const void* tau_b  = d_in[8];
    const void* cb     = d_in[9];
    const void* dec_w  = d_in[10];
    const void* dec_b  = d_in[11];
    // d_in[12] = n_steps (fixed at 5 by the problem definition)

    char* ws = (char*)d_ws;
    size_t off = 0;
    auto carve = [&](size_t bytes) -> void* {
        void* p = ws + off;
        off += (bytes + 255) & ~(size_t)255;
        return p;
    };
    u8*    idxA     = (u8*)   carve(NPIX);          // 1 MiB
    u8*    idxB     = (u8*)   carve(NPIX);          // 1 MiB
    float* wf1      = (float*)carve(9216 * 4);
    float* wf2      = (float*)carve(1024 * 4);
    float* wft      = (float*)carve(1024 * 4);
    float* cbf      = (float*)carve(8192 * 4);
    float* cn2      = (float*)carve(256 * 4);
    float* wf0      = (float*)carve(288 * 4);
    float* bias_all = (float*)carve(161 * 4);
    int*   flag     = (int*)  carve(4);

    prep_kernel<<<79, 256, 0, stream>>>(x, stem_w, stem_b, up1_w, up1_b,
                                        up2_w, up2_b, tau_w, tau_b,
                                        cb, dec_w, dec_b,
                                        wf1, wf2, wft, cbf, cn2, wf0, bias_all,
                                        flag);
    dim3 g(WW/16, HH/16, BATCH);
    // step 1: state from stem(x); steps 2..5: state = codebook[idx]
    step_kernel<<<g, 256, 0, stream>>>(0, x, flag, idxB, idxA,
                                       wf0, wf1, wf2, wft, cbf, cn2, bias_all);
    u8* cur = idxA; u8* nxt = idxB;
    for (int t = 1; t < NSTEPS; t++) {
        step_kernel<<<g, 256, 0, stream>>>(1, x, flag, cur, nxt,
                                           wf0, wf1, wf2, wft, cbf, cn2, bias_all);
        u8* tmp = cur; cur = nxt; nxt = tmp;
    }
    dec_kernel<<<NPIX/256, 256, 0, stream>>>(cur, cbf, bias_all, flag, d_out);
}

// Round 3
// 724.598 us; speedup vs baseline: 4.1342x; 4.1342x over previous
//
#include <hip/hip_runtime.h>
#include <hip/hip_bf16.h>

#define BATCH 16
#define HH 256
#define WW 256
#define NPIX (BATCH*HH*WW)   // 1,048,576
#define NSTEPS 5

using u16 = unsigned short;
using u32 = unsigned int;
using u8  = unsigned char;

typedef __attribute__((ext_vector_type(8))) short bf8_t;   // 8 bf16 = one MFMA A/B frag
typedef __attribute__((ext_vector_type(4))) float f4_t;    // MFMA C/D frag

#define MFMA16 __builtin_amdgcn_mfma_f32_16x16x32_bf16

__device__ __forceinline__ float bf2f(u32 u) {
    union { u32 i; float f; } v; v.i = u << 16; return v.f;
}
__device__ __forceinline__ u16 f2bf(float f) {
    union { float f; u32 i; } v; v.f = f;
    u32 x = v.i;
    x += 0x7fffu + ((x >> 16) & 1u);
    return (u16)(x >> 16);
}
__device__ __forceinline__ float ldin(const void* p, int i, int f32) {
    return f32 ? ((const float*)p)[i] : bf2f(((const u16*)p)[i]);
}
__device__ __forceinline__ u16 ldbf(const void* p, int i, int f32) {
    return f32 ? f2bf(((const float*)p)[i]) : ((const u16*)p)[i];
}
__device__ __forceinline__ int sniff_f32(const void* xraw) {
    const u32* xw = (const u32*)xraw;
    int cnt = 0;
    for (int j = 0; j < 64; j++) {
        u32 w = xw[j];
        float flo = bf2f(w & 0xffffu);
        float a = fabsf(flo);
        if (flo == 0.0f || (a >= 6e-8f && a <= 64.0f)) cnt++;
    }
    return (cnt < 32) ? 1 : 0;
}
__device__ __forceinline__ void store32bf(u16* __restrict__ dst, const float* src) {
    uint4 o[4];
    u32* ow = (u32*)o;
#pragma unroll
    for (int i = 0; i < 16; i++)
        ow[i] = (u32)f2bf(src[2*i]) | ((u32)f2bf(src[2*i+1]) << 16);
    uint4* d4 = (uint4*)dst;
#pragma unroll
    for (int q = 0; q < 4; q++) d4[q] = o[q];
}

// ============================ prep ============================
// Fragment layouts (16x16x32 bf16 MFMA, gfx950):
//   A-frag: lane l elem j -> A[m=l&15][k=(l>>4)*8+j]
//   B-frag: lane l elem j -> B[k=(l>>4)*8+j][n=l&15]
//   C/D:    lane l reg  r -> D[row=(l>>4)*4+r][col=l&15]
// M32[tap][k][co] = sum_ci up1_w[co][ci][tap]*cb[k][ci]  (fp32, exact)
__global__ void prep_kernel(const void* x,
    const void* stem_w, const void* stem_b, const void* up1_w, const void* up1_b,
    const void* up2_w, const void* up2_b, const void* tau_w, const void* tau_b,
    const void* cb, const void* dec_w, const void* dec_b,
    float* M32, u16* w1frag, u16* w2frag, u16* wtfrag, u16* cbfrag, u16* cb_bf,
    float* cn2, float* decdot, float* wf0,
    float* up1_bf, float* up2_bf, float* tau_bf, float* stem_bf, int* flag)
{
    int f32 = sniff_f32(x);
    int i = blockIdx.x * 256 + threadIdx.x;
    if (i == 0) *flag = f32;
    if (i < 73728) {                       // M32: [tap][k][co] = tap*8192+k*32+co
        int tap = i >> 13; int r = i & 8191; int k = r >> 5, co = r & 31;
        float s = 0.f;
        for (int ci = 0; ci < 32; ci++)
            s += ldin(up1_w, (co*32+ci)*9 + tap, f32) * ldin(cb, k*32+ci, f32);
        M32[i] = s;
        return;
    }
    i -= 73728;
    if (i < 9216) {                        // w1frag: slot=(tap*2+nt), [slot][lane][j]
        int slot = i >> 9, rem = i & 511, lane = rem >> 3, j = rem & 7;
        int tap = slot >> 1, nt = slot & 1;
        int co = nt*16 + (lane & 15), ci = (lane >> 4)*8 + j;
        w1frag[i] = ldbf(up1_w, (co*32+ci)*9 + tap, f32);
        return;
    }
    i -= 9216;
    if (i < 1024) {                        // w2frag [nt][lane][j] = up2_w[co][k]
        int nt = i >> 9, rem = i & 511, lane = rem >> 3, j = rem & 7;
        int co = nt*16 + (lane & 15), k = (lane >> 4)*8 + j;
        w2frag[i] = ldbf(up2_w, co*32 + k, f32);
        return;
    }
    i -= 1024;
    if (i < 1024) {                        // wtfrag
        int nt = i >> 9, rem = i & 511, lane = rem >> 3, j = rem & 7;
        int co = nt*16 + (lane & 15), k = (lane >> 4)*8 + j;
        wtfrag[i] = ldbf(tau_w, co*32 + k, f32);
        return;
    }
    i -= 1024;
    if (i < 8192) {                        // cbfrag [nt][lane][j] = cb[code][c]
        int nt = i >> 9, rem = i & 511, lane = rem >> 3, j = rem & 7;
        int code = nt*16 + (lane & 15), c = (lane >> 4)*8 + j;
        cbfrag[i] = ldbf(cb, code*32 + c, f32);
        return;
    }
    i -= 8192;
    if (i < 8192) { cb_bf[i] = ldbf(cb, i, f32); return; }   // verbatim rows
    i -= 8192;
    if (i < 256) {
        float s = 0.f;
        for (int c = 0; c < 32; c++) { float v = ldin(cb, i*32+c, f32); s += v*v; }
        cn2[i] = 0.5f * s;
        return;
    }
    i -= 256;
    if (i < 256) {
        float s = ldin(dec_b, 0, f32);
        for (int c = 0; c < 32; c++) s += ldin(dec_w, c, f32) * ldin(cb, i*32+c, f32);
        decdot[i] = s;
        return;
    }
    i -= 256;
    if (i < 288) {                         // wf0[tap*32+co] from stem_w (co,1,ky,kx)
        int tap = i >> 5, co = i & 31;
        wf0[i] = ldin(stem_w, co*9 + tap, f32);
        return;
    }
    i -= 288;
    if (i < 32) { up1_bf[i]  = ldin(up1_b, i, f32); return; }
    i -= 32;
    if (i < 32) { up2_bf[i]  = ldin(up2_b, i, f32); return; }
    i -= 32;
    if (i < 32) { tau_bf[i]  = ldin(tau_b, i, f32); return; }
    i -= 32;
    if (i < 32) { stem_bf[i] = ldin(stem_b, i, f32); return; }
}

// ============================ stem ============================
// conv3x3 1->32 pad1 relu; x (B,1,H,W) -> state NHWC bf16
__global__ __launch_bounds__(256) void stem_kernel(const void* __restrict__ xraw,
        const float* __restrict__ wf0, const float* __restrict__ stem_bf,
        const int* __restrict__ flagp, u16* __restrict__ state)
{
    int f32 = *flagp;
    int p = blockIdx.x * 256 + threadIdx.x;
    int b = p >> 16, y = (p >> 8) & 255, xx = p & 255;
    float xv[9];
#pragma unroll
    for (int ky = 0; ky < 3; ky++) {
#pragma unroll
        for (int kx = 0; kx < 3; kx++) {
            int yy = y + ky - 1, xc = xx + kx - 1;
            bool ok = ((unsigned)yy < 256u) && ((unsigned)xc < 256u);
            xv[ky*3+kx] = ok ? ldin(xraw, (b << 16) | (yy << 8) | xc, f32) : 0.f;
        }
    }
    float acc[32];
#pragma unroll
    for (int co = 0; co < 32; co++) acc[co] = stem_bf[co];
#pragma unroll
    for (int t = 0; t < 9; t++) {
        const float* w = &wf0[t*32];
#pragma unroll
        for (int co = 0; co < 32; co++) acc[co] = fmaf(xv[t], w[co], acc[co]);
    }
#pragma unroll
    for (int co = 0; co < 32; co++) acc[co] = fmaxf(acc[co], 0.f);
    store32bf(state + (size_t)p*32, acc);
}

// ======================= shared step tail =======================
// Input: hA, sA (A-frags), s_el[8] = s[pixel quad*4+r][nt*16+col] fp32.
// Does up2/tau MFMA, sigmoid blend, z->A-layout via per-wave LDS, VQ argmin.
__device__ __forceinline__ void tail_vq(u16* hz, int col, int quad,
    bf8_t hA, bf8_t sA, const float* s_el,
    const bf8_t* w2f, const bf8_t* wtf, const bf8_t* cbf,
    const float* cn2adj, float bu2_0, float bu2_1, float bt0, float bt1,
    u32* bkey)
{
    f4_t kz = {0.f, 0.f, 0.f, 0.f};
    f4_t d0 = MFMA16(hA, w2f[0], kz, 0, 0, 0);
    f4_t d1 = MFMA16(hA, w2f[1], kz, 0, 0, 0);
    f4_t t0 = MFMA16(sA, wtf[0], kz, 0, 0, 0);
    f4_t t1 = MFMA16(sA, wtf[1], kz, 0, 0, 0);
#pragma unroll
    for (int r = 0; r < 4; r++) {
        float dl0 = d0[r] + bu2_0;
        float tv0 = t0[r] + bt0;
        float be0 = 1.0f / (1.0f + __expf(-tv0));
        float z0  = 0.25f * (dl0 + be0 * (s_el[r] - dl0));      // 0.25 exact scale
        float dl1 = d1[r] + bu2_1;
        float tv1 = t1[r] + bt1;
        float be1 = 1.0f / (1.0f + __expf(-tv1));
        float z1  = 0.25f * (dl1 + be1 * (s_el[4+r] - dl1));
        int row = (quad*4 + r) * 32;
        hz[row + col]      = f2bf(z0);
        hz[row + 16 + col] = f2bf(z1);
    }
    asm volatile("s_waitcnt lgkmcnt(0)" ::: "memory");
    bf8_t zA = *(const bf8_t*)&hz[col*32 + quad*8];
    bkey[0] = bkey[1] = bkey[2] = bkey[3] = 0xFFFFFFFFu;
#pragma unroll
    for (int nt = 0; nt < 16; nt++) {
        f4_t sc = MFMA16(zA, cbf[nt], kz, 0, 0, 0);   // 0.25*z . c
        u32 code = (u32)(nt*16 + col);
#pragma unroll
        for (int r = 0; r < 4; r++) {
            // dist4 = 0.25*(cn2 - z.c) + 0.5 in (0.41,0.59): positive -> bits monotone
            float dd = cn2adj[nt] - sc[r];
            u32 kb = (__builtin_bit_cast(u32, dd) & 0xFFFFFF00u) | code;
            bkey[r] = kb < bkey[r] ? kb : bkey[r];
        }
    }
#pragma unroll
    for (int off = 1; off < 16; off <<= 1) {
#pragma unroll
        for (int r = 0; r < 4; r++) {
            u32 ok2 = __shfl_xor(bkey[r], off, 64);
            bkey[r] = ok2 < bkey[r] ? ok2 : bkey[r];
        }
    }
}

// ======================= step 1 (from stem state) =======================
__global__ __launch_bounds__(256, 2) void step0_kernel(
    const u16* __restrict__ sin, u8* __restrict__ idx_out,
    const u16* __restrict__ w1frag, const u16* __restrict__ w2frag,
    const u16* __restrict__ wtfrag, const u16* __restrict__ cbfrag,
    const u16* __restrict__ cb_bf, const float* __restrict__ cn2,
    const float* __restrict__ up1_b, const float* __restrict__ up2_b,
    const float* __restrict__ tau_b)
{
    __shared__ u16 hzbuf[4*512];
    int tid = threadIdx.x;
    int lane = tid & 63, wave = tid >> 6;
    int col = lane & 15, quad = lane >> 4;
    int b = blockIdx.z, x0 = blockIdx.x * 16;
    u16* hz = &hzbuf[wave*512];

    bf8_t w1f[18], w2f[2], wtf[2], cbf[16];
#pragma unroll
    for (int t2 = 0; t2 < 18; t2++) w1f[t2] = *(const bf8_t*)&w1frag[(t2*64+lane)*8];
#pragma unroll
    for (int nt = 0; nt < 2; nt++) {
        w2f[nt] = *(const bf8_t*)&w2frag[(nt*64+lane)*8];
        wtf[nt] = *(const bf8_t*)&wtfrag[(nt*64+lane)*8];
    }
#pragma unroll
    for (int nt = 0; nt < 16; nt++) cbf[nt] = *(const bf8_t*)&cbfrag[(nt*64+lane)*8];
    float cn2adj[16];
#pragma unroll
    for (int nt = 0; nt < 16; nt++) cn2adj[nt] = 0.25f*cn2[nt*16+col] + 0.5f;
    float bu1C0 = up1_b[col], bu1C1 = up1_b[col+16];
    float bu2_0 = up2_b[col], bu2_1 = up2_b[col+16];
    float bt0 = tau_b[col],   bt1 = tau_b[col+16];
    f4_t kz = {0.f, 0.f, 0.f, 0.f};

    for (int rr = 0; rr < 4; rr++) {
        int y = blockIdx.y*16 + wave*4 + rr;
        int rowb = (b*256 + y)*256;
        f4_t a0 = kz, a1 = kz;
        bf8_t sA = {0,0,0,0,0,0,0,0};
#pragma unroll
        for (int tap = 0; tap < 9; tap++) {
            int dy = tap/3 - 1, dx = tap%3 - 1;
            int yy = y + dy, xx = x0 + dx + col;
            bf8_t af = {0,0,0,0,0,0,0,0};
            if (((unsigned)yy < 256u) & ((unsigned)xx < 256u))
                af = *(const bf8_t*)&sin[(size_t)((b*256+yy)*256+xx)*32 + quad*8];
            if (tap == 4) sA = af;
            a0 = MFMA16(af, w1f[tap*2+0], a0, 0, 0, 0);
            a1 = MFMA16(af, w1f[tap*2+1], a1, 0, 0, 0);
        }
#pragma unroll
        for (int r = 0; r < 4; r++) {
            int row = (quad*4 + r) * 32;
            hz[row + col]      = f2bf(fmaxf(a0[r] + bu1C0, 0.f));
            hz[row + 16 + col] = f2bf(fmaxf(a1[r] + bu1C1, 0.f));
        }
        asm volatile("s_waitcnt lgkmcnt(0)" ::: "memory");
        bf8_t hA = *(const bf8_t*)&hz[col*32 + quad*8];
        float s_el[8];
#pragma unroll
        for (int r = 0; r < 4; r++) {
            size_t pb = (size_t)(rowb + x0 + quad*4 + r) * 32;
            s_el[r]   = bf2f(sin[pb + col]);
            s_el[4+r] = bf2f(sin[pb + 16 + col]);
        }
        u32 bkey[4];
        tail_vq(hz, col, quad, hA, sA, s_el, w2f, wtf, cbf, cn2adj,
                bu2_0, bu2_1, bt0, bt1, bkey);
        if (col < 4)
            idx_out[rowb + x0 + quad*4 + col] = (u8)(bkey[col] & 255u);
    }
}

// ======================= steps 2..5 (from idx, table conv) =======================
__global__ __launch_bounds__(256, 2) void step1_kernel(
    const u8* __restrict__ idx_in, u8* __restrict__ idx_out,
    const float* __restrict__ M32,
    const u16* __restrict__ w2frag, const u16* __restrict__ wtfrag,
    const u16* __restrict__ cbfrag, const u16* __restrict__ cb_bf,
    const float* __restrict__ cn2, const float* __restrict__ up1_b,
    const float* __restrict__ up2_b, const float* __restrict__ tau_b)
{
    __shared__ u16 hzbuf[4*512];
    int tid = threadIdx.x;
    int lane = tid & 63, wave = tid >> 6;
    int col = lane & 15, quad = lane >> 4;
    int b = blockIdx.z, x0 = blockIdx.x * 16;
    u16* hz = &hzbuf[wave*512];

    bf8_t w2f[2], wtf[2], cbf[16];
#pragma unroll
    for (int nt = 0; nt < 2; nt++) {
        w2f[nt] = *(const bf8_t*)&w2frag[(nt*64+lane)*8];
        wtf[nt] = *(const bf8_t*)&wtfrag[(nt*64+lane)*8];
    }
#pragma unroll
    for (int nt = 0; nt < 16; nt++) cbf[nt] = *(const bf8_t*)&cbfrag[(nt*64+lane)*8];
    float cn2adj[16];
#pragma unroll
    for (int nt = 0; nt < 16; nt++) cn2adj[nt] = 0.25f*cn2[nt*16+col] + 0.5f;
    float bu1A[8];
#pragma unroll
    for (int j = 0; j < 8; j++) bu1A[j] = up1_b[quad*8 + j];
    float bu2_0 = up2_b[col], bu2_1 = up2_b[col+16];
    float bt0 = tau_b[col],   bt1 = tau_b[col+16];

    for (int rr = 0; rr < 4; rr++) {
        int y = blockIdx.y*16 + wave*4 + rr;
        int rowb = (b*256 + y)*256;
        int kk[9];
#pragma unroll
        for (int tap = 0; tap < 9; tap++) {
            int dy = tap/3 - 1, dx = tap%3 - 1;
            int yy = y + dy, xx = x0 + dx + col;
            bool ok = ((unsigned)yy < 256u) & ((unsigned)xx < 256u);
            kk[tap] = ok ? (int)idx_in[(b*256+yy)*256 + xx] : -1;
        }
        int kp[4];
#pragma unroll
        for (int r = 0; r < 4; r++) kp[r] = (int)idx_in[rowb + x0 + quad*4 + r];

        float hacc[8];                       // h in A-layout: h[col][quad*8+j]
#pragma unroll
        for (int j = 0; j < 8; j++) hacc[j] = bu1A[j];
#pragma unroll
        for (int tap = 0; tap < 9; tap++) {
            if (kk[tap] >= 0) {
                const f4_t* mp = (const f4_t*)&M32[(tap*256 + kk[tap])*32 + quad*8];
                f4_t m0 = mp[0], m1 = mp[1];
                hacc[0]+=m0[0]; hacc[1]+=m0[1]; hacc[2]+=m0[2]; hacc[3]+=m0[3];
                hacc[4]+=m1[0]; hacc[5]+=m1[1]; hacc[6]+=m1[2]; hacc[7]+=m1[3];
            }
        }
        union { u32 w[4]; bf8_t v; } hu;
#pragma unroll
        for (int j2 = 0; j2 < 4; j2++) {
            float a = fmaxf(hacc[2*j2],   0.f);
            float c = fmaxf(hacc[2*j2+1], 0.f);
            hu.w[j2] = (u32)f2bf(a) | ((u32)f2bf(c) << 16);
        }
        bf8_t hA = hu.v;
        bf8_t sA = *(const bf8_t*)&cb_bf[kk[4]*32 + quad*8];
        float s_el[8];
#pragma unroll
        for (int r = 0; r < 4; r++) {
            s_el[r]   = bf2f(cb_bf[kp[r]*32 + col]);
            s_el[4+r] = bf2f(cb_bf[kp[r]*32 + 16 + col]);
        }
        u32 bkey[4];
        tail_vq(hz, col, quad, hA, sA, s_el, w2f, wtf, cbf, cn2adj,
                bu2_0, bu2_1, bt0, bt1, bkey);
        if (col < 4)
            idx_out[rowb + x0 + quad*4 + col] = (u8)(bkey[col] & 255u);
    }
}

// ============================ dec ============================
__global__ __launch_bounds__(256) void dec_kernel(const u8* __restrict__ idx,
        const float* __restrict__ decdot, const int* __restrict__ flagp,
        void* __restrict__ out)
{
    int p = blockIdx.x * 256 + threadIdx.x;
    float s = decdot[idx[p]];
    float r = 1.0f / (1.0f + __expf(-s));
    if (*flagp) ((float*)out)[p] = r;
    else        ((u16*)out)[p]   = f2bf(r);
}

extern "C" void kernel_launch(void* const* d_in, const int* in_sizes, int n_in,
                              void* d_out, int out_size, void* d_ws, size_t ws_size,
                              hipStream_t stream)
{
    const void* x      = d_in[0];
    const void* stem_w = d_in[1];
    const void* stem_b = d_in[2];
    const void* up1_w  = d_in[3];
    const void* up1_b  = d_in[4];
    const void* up2_w  = d_in[5];
    const void* up2_b  = d_in[6];
    const void* tau_w  = d_in[7];
    const void* tau_b  = d_in[8];
    const void* cb     = d_in[9];
    const void* dec_w  = d_in[10];
    const void* dec_b  = d_in[11];
    // d_in[12] = n_steps (fixed at 5 by the problem definition)

    char* ws = (char*)d_ws;
    size_t off = 0;
    auto carve = [&](size_t bytes) -> void* {
        void* p = ws + off;
        off += (bytes + 255) & ~(size_t)255;
        return p;
    };
    u16*   state   = (u16*)  carve((size_t)NPIX * 32 * 2);  // 67.1 MB (stem output)
    u8*    idxA    = (u8*)   carve(NPIX);
    u8*    idxB    = (u8*)   carve(NPIX);
    float* M32     = (float*)carve(73728 * 4);              // 288 KB conv table
    u16*   w1frag  = (u16*)  carve(9216 * 2);
    u16*   w2frag  = (u16*)  carve(1024 * 2);
    u16*   wtfrag  = (u16*)  carve(1024 * 2);
    u16*   cbfrag  = (u16*)  carve(8192 * 2);
    u16*   cb_bf   = (u16*)  carve(8192 * 2);
    float* cn2     = (float*)carve(256 * 4);
    float* decdot  = (float*)carve(256 * 4);
    float* wf0     = (float*)carve(288 * 4);
    float* up1_bf  = (float*)carve(32 * 4);
    float* up2_bf  = (float*)carve(32 * 4);
    float* tau_bf  = (float*)carve(32 * 4);
    float* stem_bf = (float*)carve(32 * 4);
    int*   flag    = (int*)  carve(4);

    prep_kernel<<<400, 256, 0, stream>>>(x, stem_w, stem_b, up1_w, up1_b,
        up2_w, up2_b, tau_w, tau_b, cb, dec_w, dec_b,
        M32, w1frag, w2frag, wtfrag, cbfrag, cb_bf,
        cn2, decdot, wf0, up1_bf, up2_bf, tau_bf, stem_bf, flag);

    stem_kernel<<<NPIX/256, 256, 0, stream>>>(x, wf0, stem_bf, flag, state);

    dim3 g(WW/16, HH/16, BATCH);
    step0_kernel<<<g, 256, 0, stream>>>(state, idxA, w1frag, w2frag, wtfrag,
                                        cbfrag, cb_bf, cn2, up1_bf, up2_bf, tau_bf);
    u8* cur = idxA; u8* nxt = idxB;
    for (int t = 1; t < NSTEPS; t++) {
        step1_kernel<<<g, 256, 0, stream>>>(cur, nxt, M32, w2frag, wtfrag,
                                            cbfrag, cb_bf, cn2, up1_bf, up2_bf, tau_bf);
        u8* tmp = cur; cur = nxt; nxt = tmp;
    }
    dec_kernel<<<NPIX/256, 256, 0, stream>>>(cur, decdot, flag, d_out);
}